// Round 8
// baseline (315.091 us; speedup 1.0000x reference)
//
#include <hip/hip_runtime.h>
#include <hip/hip_bf16.h>
#include <stdint.h>

// LocalAttention: B=16, N=1024 (32x32 grid), C=1024, H=16, D=64.
// cvt->bf16 (fused) ; GEMM1 qkv=x@w_qkv^T ; local 3x3 window attention ;
// GEMM2 out=attn@w_proj^T+b. Workspace ~176.2 MB.
//
// GEMM structure (round 8): A (activations) staged HBM->LDS via
// global_load_lds, T2-swizzled, 2-deep double buffer. B (weights, L2-resident,
// 6.3/2.1 MB) is read DIRECTLY global->registers, double-buffered 1 tile ahead
// -- this halves LDS traffic (96->64 ds_read_b128/tile/CU, 32->16 KB writes),
// un-serializing the CU's LDS pipe from the MFMA pipe (r6/r7 analysis: LDS
// ~1150cy + MFMA ~1240cy were running back-to-back per 2810cy tile).

typedef __bf16 bf16;
typedef __bf16 bf16x4_t __attribute__((ext_vector_type(4)));
typedef __bf16 bf16x8_t __attribute__((ext_vector_type(8)));
typedef float f32x4_t __attribute__((ext_vector_type(4)));

static __device__ __forceinline__ void gload_lds16(const void* g, void* l) {
  __builtin_amdgcn_global_load_lds((__attribute__((address_space(1))) void*)g,
                                   (__attribute__((address_space(3))) void*)l,
                                   16, 0, 0);
}

// raw s_barrier with compile-time memory fences (no vmcnt/lgkm drain)
static __device__ __forceinline__ void block_barrier() {
  asm volatile("" ::: "memory");
  __builtin_amdgcn_s_barrier();
  asm volatile("" ::: "memory");
}

// ---------------- fused f32 -> bf16 conversion (x, w_qkv, w_proj) --------------
__global__ void cvt_all(const float* __restrict__ x, const float* __restrict__ wq,
                        const float* __restrict__ wp, bf16* __restrict__ xb,
                        bf16* __restrict__ wqb, bf16* __restrict__ wpb) {
  constexpr int NX = 4194304, NWQ = 786432;          // float4 counts
  int i = blockIdx.x * blockDim.x + threadIdx.x;     // grid exactly covers total
  const float* src; bf16* dst; int off;
  if (i < NX)            { src = x;  dst = xb;  off = i; }
  else if (i < NX + NWQ) { src = wq; dst = wqb; off = i - NX; }
  else                   { src = wp; dst = wpb; off = i - (NX + NWQ); }
  float4 v = reinterpret_cast<const float4*>(src)[off];
  bf16x4_t o;
  o[0] = (bf16)v.x; o[1] = (bf16)v.y; o[2] = (bf16)v.z; o[3] = (bf16)v.w;
  reinterpret_cast<bf16x4_t*>(dst)[off] = o;
}

// ---------------- BMx256 8-wave bf16 GEMM, C = A @ B^T, BK=32 ------------------
// A: [M][K] staged to LDS (2 slots, T2-swizzled); B: [N][K] direct to regs.
// 512 threads = 8 waves (2M x 4N). MWF=8 -> BM=256 (GEMM1), 4 -> BM=128 (GEMM2).
// Per tile per wave: MWF ds_read_b128 (A) + 4 global dwordx4 (B, for kt+1) +
// ALOADS global_load_lds (A, for kt+2) + 4*MWF MFMA.
// vmcnt discipline (per-wave FIFO): issue order ... A(kt+1)@kt-1, B(kt+1)@kt-top,
// A(kt+2)@kt-end; tile-end vmcnt(ALOADS) leaves only A(kt+2) outstanding ->
// certifies A(kt+1) and B(kt+1) landed before the next body. Never drains in
// the main loop. Barrier before stageA certifies slot consumption block-wide.
template<int OUT_BF16, int MWF>
__global__ __launch_bounds__(512, 2)
void gemm_breg(const bf16* __restrict__ A, const bf16* __restrict__ Bm,
               void* __restrict__ Cout, const float* __restrict__ bias,
               int M, int N, int K) {
  constexpr int BM      = MWF * 32;
  constexpr int A_BYTES = BM * 64;           // A tile bytes (BM x 32 bf16)
  constexpr int ALOADS  = MWF / 4;           // per-thread A staging loads (2 or 1)
  __shared__ __align__(16) char lds[2 * A_BYTES];

  const int tid = threadIdx.x;
  const int w = tid >> 6, lane = tid & 63;
  const int fr = lane & 15, g = lane >> 4;
  const int wr = w >> 2, wc = w & 3;          // wave grid 2 x 4

  // T1: XCD-aware bijective swizzle (nwg % 8 == 0 for both call sites)
  const int nwg = gridDim.x * gridDim.y;
  int lid = blockIdx.y * gridDim.x + blockIdx.x;
  lid = (lid & 7) * (nwg >> 3) + (lid >> 3);
  const int bx = lid % gridDim.x, by = lid / gridDim.x;
  const int row0 = by * BM, col0 = bx * 256;

  const bf16* Ag = A + (size_t)row0 * K;
  const int srow = tid >> 2;                                // 0..127
  const int scol = ((tid & 3) ^ ((tid >> 3) & 3)) * 8;      // inverse-swizzled col
  const int nkt  = K >> 5;                                  // even (K=1024 -> 32)

  // per-lane B base: col = col0 + wc*64 + j*16 + fr, k-chunk = g*8
  const bf16* Bl = Bm + (size_t)(col0 + wc * 64 + fr) * K + g * 8;

  f32x4_t acc[MWF][4] = {};

  auto stageA = [&](int kt, int slot) {
    const int kb = kt << 5;
    char* sb = lds + slot * A_BYTES;
#pragma unroll
    for (int n = 0; n < ALOADS; ++n)
      gload_lds16(Ag + (size_t)(n * 128 + srow) * K + kb + scol,
                  sb + n * 8192 + tid * 16);
  };
  auto loadB = [&](bf16x8_t (&bv)[4], int kt) {
    const int kb = kt << 5;
#pragma unroll
    for (int j = 0; j < 4; ++j)
      bv[j] = *reinterpret_cast<const bf16x8_t*>(Bl + (size_t)(j * 16) * K + kb);
  };

  const int uxor = ((fr >> 1) & 3) << 4;   // T2 read-side XOR (lane-constant)

  auto body = [&](int kt, const bf16x8_t (&bv)[4], bf16x8_t (&bnxt)[4],
                  bool pfB, bool pfA) {
    if (pfB) loadB(bnxt, kt + 1);          // B for next tile: full body of cover
    const char* cA = lds + (kt & 1) * A_BYTES;
    bf16x8_t a[MWF];
#pragma unroll
    for (int i = 0; i < MWF; ++i) {
      const int row = wr * (MWF * 16) + i * 16 + fr;
      a[i] = *reinterpret_cast<const bf16x8_t*>(cA + (row << 6) + ((g << 4) ^ uxor));
    }
#pragma unroll
    for (int i = 0; i < MWF; ++i)
#pragma unroll
      for (int j = 0; j < 4; ++j)
        acc[i][j] = __builtin_amdgcn_mfma_f32_16x16x32_bf16(a[i], bv[j], acc[i][j], 0, 0, 0);
    // every wave's ds_reads of this slot are consumed above -> after this
    // barrier the slot is certifiably free block-wide
    block_barrier();
    if (pfA) {
      stageA(kt + 2, kt & 1);
      if constexpr (ALOADS == 2) asm volatile("s_waitcnt vmcnt(2)" ::: "memory");
      else                       asm volatile("s_waitcnt vmcnt(1)" ::: "memory");
    } else {
      asm volatile("s_waitcnt vmcnt(0)" ::: "memory");
    }
    block_barrier();
  };

  // prologue: A tiles 0,1 staged; B tile 0 in regs; leave A(1) in flight
  stageA(0, 0);
  stageA(1, 1);
  bf16x8_t bA_[4], bB_[4];
  loadB(bA_, 0);
  if constexpr (ALOADS == 2) asm volatile("s_waitcnt vmcnt(2)" ::: "memory");
  else                       asm volatile("s_waitcnt vmcnt(1)" ::: "memory");
  block_barrier();

  for (int kt = 0; kt < nkt; kt += 2) {
    body(kt,     bA_, bB_, kt + 1 < nkt, kt + 2 < nkt);
    body(kt + 1, bB_, bA_, kt + 2 < nkt, kt + 3 < nkt);
  }

  // epilogue: D row = g*4+r (M), col = fr (N) per verified m89 layout
#pragma unroll
  for (int fm = 0; fm < MWF; ++fm) {
    const int rbase = row0 + wr * (MWF * 16) + fm * 16 + g * 4;
#pragma unroll
    for (int fn = 0; fn < 4; ++fn) {
      const int col = col0 + wc * 64 + fn * 16 + fr;
#pragma unroll
      for (int r = 0; r < 4; ++r) {
        const size_t idx = (size_t)(rbase + r) * N + col;
        if constexpr (OUT_BF16) {
          reinterpret_cast<bf16*>(Cout)[idx] = (bf16)acc[fm][fn][r];
        } else {
          reinterpret_cast<float*>(Cout)[idx] = acc[fm][fn][r] + bias[col];
        }
      }
    }
  }
}

// ---------------- local 3x3 window attention -----------------------------------
// qkv: [B*N][3072] bf16 (q|k|v, head h at h*64). out: [B*N][1024] bf16.
// 8 tokens per wave; 8 lanes per token, each lane owns an 8-elem d-chunk (16B).
__global__ __launch_bounds__(256)
void local_attn(const bf16* __restrict__ qkv, bf16* __restrict__ outp) {
  const int tid  = threadIdx.x;
  const int wave = tid >> 6, lane = tid & 63;
  const int tsub = lane >> 3, ch = lane & 7;
  const int gt = (blockIdx.x * 4 + wave) * 8 + tsub;
  const int i  = gt & 1023;
  const int bh = gt >> 10;
  const int h  = bh & 15, b = bh >> 4;
  const int r  = i >> 5, c = i & 31;

  const bf16* base = qkv + (size_t)(b * 1024) * 3072 + h * 64 + ch * 8;

  bf16x8_t qv = *reinterpret_cast<const bf16x8_t*>(base + (size_t)i * 3072);
  float qf[8];
#pragma unroll
  for (int e = 0; e < 8; ++e) qf[e] = (float)qv[e];

  float s[9];
  bool valid[9];
#pragma unroll
  for (int dr = -1; dr <= 1; ++dr) {
#pragma unroll
    for (int dc = -1; dc <= 1; ++dc) {
      const int idx = (dr + 1) * 3 + (dc + 1);
      const int rr = r + dr, cc = c + dc;
      valid[idx] = (rr >= 0 && rr < 32 && cc >= 0 && cc < 32);
      float sv = -1e30f;
      if (valid[idx]) {
        const int j = rr * 32 + cc;
        bf16x8_t kv = *reinterpret_cast<const bf16x8_t*>(base + (size_t)j * 3072 + 1024);
        float ps = 0.f;
#pragma unroll
        for (int e = 0; e < 8; ++e) ps += qf[e] * (float)kv[e];
        ps += __shfl_xor(ps, 1);
        ps += __shfl_xor(ps, 2);
        ps += __shfl_xor(ps, 4);
        sv = ps * 0.125f;
      }
      s[idx] = sv;
    }
  }

  float mx = s[0];
#pragma unroll
  for (int t = 1; t < 9; ++t) mx = fmaxf(mx, s[t]);

  float p[9], denom = 0.f;
#pragma unroll
  for (int t = 0; t < 9; ++t) {
    p[t] = valid[t] ? __expf(s[t] - mx) : 0.f;
    denom += p[t];
  }

  float o[8] = {};
#pragma unroll
  for (int dr = -1; dr <= 1; ++dr) {
#pragma unroll
    for (int dc = -1; dc <= 1; ++dc) {
      const int idx = (dr + 1) * 3 + (dc + 1);
      if (valid[idx]) {
        const int j = (r + dr) * 32 + (c + dc);
        bf16x8_t vv = *reinterpret_cast<const bf16x8_t*>(base + (size_t)j * 3072 + 2048);
        const float pw = p[idx];
#pragma unroll
        for (int e = 0; e < 8; ++e) o[e] += pw * (float)vv[e];
      }
    }
  }

  const float inv = 1.f / denom;
  bf16x8_t ov;
#pragma unroll
  for (int e = 0; e < 8; ++e) ov[e] = (bf16)(o[e] * inv);
  *reinterpret_cast<bf16x8_t*>(outp + (size_t)(b * 1024 + i) * 1024 + h * 64 + ch * 8) = ov;
}

extern "C" void kernel_launch(void* const* d_in, const int* in_sizes, int n_in,
                              void* d_out, int out_size, void* d_ws, size_t ws_size,
                              hipStream_t stream) {
  const float* x      = (const float*)d_in[0];
  const float* w_qkv  = (const float*)d_in[1];
  const float* w_proj = (const float*)d_in[2];
  const float* b_proj = (const float*)d_in[3];
  float* out = (float*)d_out;

  const size_t nx   = (size_t)16384 * 1024;
  const size_t nwq  = (size_t)3072 * 1024;
  const size_t nwp  = (size_t)1024 * 1024;
  const size_t nqkv = (size_t)16384 * 3072;

  bf16* x_bf  = (bf16*)d_ws;
  bf16* wq_bf = x_bf + nx;
  bf16* wp_bf = wq_bf + nwq;
  bf16* qkv   = wp_bf + nwp;
  bf16* attn  = qkv + nqkv;

  // fused cvt: (nx+nwq+nwp)/4 float4s = 5242880 -> 20480 blocks x 256
  cvt_all<<<20480, 256, 0, stream>>>(x, w_qkv, w_proj, x_bf, wq_bf, wp_bf);

  // qkv = x @ w_qkv^T : M=16384, N=3072, K=1024 ; BM=256 ; grid 12x64=768 (%8==0)
  gemm_breg<1, 8><<<dim3(3072 / 256, 16384 / 256), 512, 0, stream>>>(
      x_bf, wq_bf, qkv, nullptr, 16384, 3072, 1024);

  // local window attention: 262144 tokens, 32 tokens/block
  local_attn<<<8192, 256, 0, stream>>>(qkv, attn);

  // out = attn @ w_proj^T + b : M=16384, N=1024, K=1024 ; BM=128 ; grid 4x128=512
  gemm_breg<0, 4><<<dim3(1024 / 256, 16384 / 128), 512, 0, stream>>>(
      attn, wp_bf, out, b_proj, 16384, 1024, 1024);
}

// Round 9
// 217.099 us; speedup vs baseline: 1.4514x; 1.4514x over previous
//
#include <hip/hip_runtime.h>
#include <hip/hip_bf16.h>
#include <stdint.h>

// LocalAttention: B=16, N=1024 (32x32 grid), C=1024, H=16, D=64.
// cvt->bf16 (fused) ; GEMM1 qkv=x@w_qkv^T ; local 3x3 window attention ;
// GEMM2 out=attn@w_proj^T+b. Workspace ~176.2 MB.
//
// GEMM (round 9): faithful m201 8-phase port. BK=64, 2 LDS buffers of 64KB
// (A 256x64 + B 256x64 bf16), T2-swizzled. 4 phases/K-tile, zig-zag quadrants
// (00,01,11,10), each fragment read once. EVERY phase stages exactly 2
// global_load_lds (16KB half-tile): tile tau's 8 units issue at
// {tau-2.ph2: B u01 | tau-2.ph3: A u01 | tau-1.ph0: A u23 | tau-1.ph1: B u23},
// each into a region certified consumed by the preceding post-MFMA barrier
// (B reads drain by ph1, A reads by ph2). Counted vmcnt(4) ONLY at tile
// boundaries (never drains in-loop): waits tile t+1 resident, leaves the 4
// newest (tile t+2's first units) in flight. A gets >=4 phases (~1000cy) HBM
// cover; B is L2-hot. r5's failure isolated to: BK=32 (2x barrier density) +
// clustered 4+4 staging + per-tile vmcnt(8) -- all fixed here per m196/m218.

typedef __bf16 bf16;
typedef __bf16 bf16x4_t __attribute__((ext_vector_type(4)));
typedef __bf16 bf16x8_t __attribute__((ext_vector_type(8)));
typedef float f32x4_t __attribute__((ext_vector_type(4)));

static __device__ __forceinline__ void gload_lds16(const void* g, void* l) {
  __builtin_amdgcn_global_load_lds((__attribute__((address_space(1))) void*)g,
                                   (__attribute__((address_space(3))) void*)l,
                                   16, 0, 0);
}

// raw s_barrier with compile-time memory fences (no vmcnt/lgkm drain)
static __device__ __forceinline__ void block_barrier() {
  asm volatile("" ::: "memory");
  __builtin_amdgcn_s_barrier();
  asm volatile("" ::: "memory");
}

// ---------------- fused f32 -> bf16 conversion (x, w_qkv, w_proj) --------------
__global__ void cvt_all(const float* __restrict__ x, const float* __restrict__ wq,
                        const float* __restrict__ wp, bf16* __restrict__ xb,
                        bf16* __restrict__ wqb, bf16* __restrict__ wpb) {
  constexpr int NX = 4194304, NWQ = 786432;          // float4 counts
  int i = blockIdx.x * blockDim.x + threadIdx.x;     // grid exactly covers total
  const float* src; bf16* dst; int off;
  if (i < NX)            { src = x;  dst = xb;  off = i; }
  else if (i < NX + NWQ) { src = wq; dst = wqb; off = i - NX; }
  else                   { src = wp; dst = wpb; off = i - (NX + NWQ); }
  float4 v = reinterpret_cast<const float4*>(src)[off];
  bf16x4_t o;
  o[0] = (bf16)v.x; o[1] = (bf16)v.y; o[2] = (bf16)v.z; o[3] = (bf16)v.w;
  reinterpret_cast<bf16x4_t*>(dst)[off] = o;
}

// ---------------- 256x256 8-wave bf16 GEMM, C = A @ B^T, BK=64, 8-phase --------
// A: [M][K], Bm: [N][K] (both K-major). 512 threads = 8 waves (2M x 4N).
// Staging unit = 64 rows x 64 cols bf16 = 8KB = 1 gload_lds/thread.
template<int OUT_BF16>
__global__ __launch_bounds__(512, 2)
void gemm8p(const bf16* __restrict__ A, const bf16* __restrict__ Bm,
            void* __restrict__ Cout, const float* __restrict__ bias,
            int M, int N, int K) {
  constexpr int SLOT = 65536;                // A 32KB + B 32KB
  extern __shared__ __align__(16) char lds[];

  const int tid = threadIdx.x;
  const int w = tid >> 6, lane = tid & 63;
  const int fr = lane & 15, g = lane >> 4;
  const int wr = w >> 2, wc = w & 3;          // wave grid 2 x 4

  // T1: XCD-aware bijective swizzle (nwg % 8 == 0 for both call sites)
  const int nwg = gridDim.x * gridDim.y;
  int lid = blockIdx.y * gridDim.x + blockIdx.x;
  lid = (lid & 7) * (nwg >> 3) + (lid >> 3);
  const int bx = lid % gridDim.x, by = lid / gridDim.x;
  const int row0 = by * 256, col0 = bx * 256;

  const bf16* Ag = A + (size_t)row0 * K;
  const bf16* Bg = Bm + (size_t)col0 * K;
  const int srow = tid >> 3;                          // 0..63 (128B rows, 8 thr/row)
  const int scol = ((tid & 7) ^ (srow & 7)) * 8;      // inverse-swizzled src col
  const int nkt  = K >> 6;                            // 16

  f32x4_t acc[8][4] = {};

  auto stA = [&](int kt, int u) {   // A unit u: rows [u*64, u*64+64)
    gload_lds16(Ag + (size_t)(u * 64 + srow) * K + (kt << 6) + scol,
                lds + (kt & 1) * SLOT + u * 8192 + tid * 16);
  };
  auto stB = [&](int kt, int u) {   // B unit u
    gload_lds16(Bg + (size_t)(u * 64 + srow) * K + (kt << 6) + scol,
                lds + (kt & 1) * SLOT + 32768 + u * 8192 + tid * 16);
  };

  const int axor = (fr & 7) << 4;   // T2 read-side XOR (lane-constant)

  // prologue: tile 0 fully (8 units) + tile 1's first 4 units; wait tile 0
  stB(0, 0); stB(0, 1); stA(0, 0); stA(0, 1); stA(0, 2); stA(0, 3);
  stB(0, 2); stB(0, 3);
  stB(1, 0); stB(1, 1); stA(1, 0); stA(1, 1);
  asm volatile("s_waitcnt vmcnt(4)" ::: "memory");
  block_barrier();

  for (int kt = 0; kt < nkt; ++kt) {
    const char* cA = lds + (kt & 1) * SLOT;
    const char* cB = cA + 32768;
    const bool p1 = (kt + 1 < nkt), p2 = (kt + 2 < nkt);

    bf16x8_t a0[4][2], a1[4][2], b0[2][2], b1[2][2];

    auto lda = [&](bf16x8_t (&d)[4][2], int q) {      // 8 ds_read_b128
#pragma unroll
      for (int i = 0; i < 4; ++i) {
        const int row = wr * 128 + (q * 4 + i) * 16 + fr;
#pragma unroll
        for (int kh = 0; kh < 2; ++kh)
          d[i][kh] = *reinterpret_cast<const bf16x8_t*>(
              cA + (row << 7) + (((kh << 6) + (g << 4)) ^ axor));
      }
    };
    auto ldb = [&](bf16x8_t (&d)[2][2], int q) {      // 4 ds_read_b128
#pragma unroll
      for (int j = 0; j < 2; ++j) {
        const int row = wc * 64 + (q * 2 + j) * 16 + fr;
#pragma unroll
        for (int kh = 0; kh < 2; ++kh)
          d[j][kh] = *reinterpret_cast<const bf16x8_t*>(
              cB + (row << 7) + (((kh << 6) + (g << 4)) ^ axor));
      }
    };
    auto mf = [&](bf16x8_t (&a)[4][2], bf16x8_t (&b)[2][2], int mi, int nj) {
      __builtin_amdgcn_s_setprio(1);
#pragma unroll
      for (int i = 0; i < 4; ++i)
#pragma unroll
        for (int j = 0; j < 2; ++j)
#pragma unroll
          for (int kh = 0; kh < 2; ++kh)
            acc[mi + i][nj + j] = __builtin_amdgcn_mfma_f32_16x16x32_bf16(
                a[i][kh], b[j][kh], acc[mi + i][nj + j], 0, 0, 0);
      __builtin_amdgcn_s_setprio(0);
    };

    // ---- ph0: 12 ds_reads; stage A(t+1) u2,u3 (first write of those regions)
    lda(a0, 0); ldb(b0, 0);
    if (p1) { stA(kt + 1, 2); stA(kt + 1, 3); }
    asm volatile("s_waitcnt lgkmcnt(8)" ::: "memory");
    block_barrier();
    asm volatile("s_waitcnt lgkmcnt(0)" ::: "memory");
    __builtin_amdgcn_sched_barrier(0);
    mf(a0, b0, 0, 0);
    block_barrier();

    // ---- ph1: 4 ds_reads; stage B(t+1) u2,u3 (first write)
    ldb(b1, 1);
    if (p1) { stB(kt + 1, 2); stB(kt + 1, 3); }
    block_barrier();
    asm volatile("s_waitcnt lgkmcnt(0)" ::: "memory");
    __builtin_amdgcn_sched_barrier(0);
    mf(a0, b1, 0, 2);
    block_barrier();   // certifies ALL B reads of this slot drained block-wide

    // ---- ph2: 8 ds_reads; stage B(t+2) u0,u1 into freed B region
    lda(a1, 1);
    if (p2) { stB(kt + 2, 0); stB(kt + 2, 1); }
    block_barrier();
    asm volatile("s_waitcnt lgkmcnt(0)" ::: "memory");
    __builtin_amdgcn_sched_barrier(0);
    mf(a1, b1, 4, 2);
    block_barrier();   // certifies ALL A reads of this slot drained block-wide

    // ---- ph3: stage A(t+2) u0,u1 into freed A region; boundary vmcnt
    if (p2) { stA(kt + 2, 0); stA(kt + 2, 1); }
    block_barrier();
    __builtin_amdgcn_sched_barrier(0);
    mf(a1, b0, 4, 0);
    if (p2) asm volatile("s_waitcnt vmcnt(4)" ::: "memory");  // t+1 resident
    else    asm volatile("s_waitcnt vmcnt(0)" ::: "memory");  // tail drain
    block_barrier();
  }

  // epilogue: D row = g*4+r (M), col = fr (N) per verified m89 layout
#pragma unroll
  for (int fm = 0; fm < 8; ++fm) {
    const int rbase = row0 + wr * 128 + fm * 16 + g * 4;
#pragma unroll
    for (int fn = 0; fn < 4; ++fn) {
      const int col = col0 + wc * 64 + fn * 16 + fr;
#pragma unroll
      for (int r = 0; r < 4; ++r) {
        const size_t idx = (size_t)(rbase + r) * N + col;
        if constexpr (OUT_BF16) {
          reinterpret_cast<bf16*>(Cout)[idx] = (bf16)acc[fm][fn][r];
        } else {
          reinterpret_cast<float*>(Cout)[idx] = acc[fm][fn][r] + bias[col];
        }
      }
    }
  }
}

// ---------------- local 3x3 window attention -----------------------------------
// qkv: [B*N][3072] bf16 (q|k|v, head h at h*64). out: [B*N][1024] bf16.
// 8 tokens per wave; 8 lanes per token, each lane owns an 8-elem d-chunk (16B).
__global__ __launch_bounds__(256)
void local_attn(const bf16* __restrict__ qkv, bf16* __restrict__ outp) {
  const int tid  = threadIdx.x;
  const int wave = tid >> 6, lane = tid & 63;
  const int tsub = lane >> 3, ch = lane & 7;
  const int gt = (blockIdx.x * 4 + wave) * 8 + tsub;
  const int i  = gt & 1023;
  const int bh = gt >> 10;
  const int h  = bh & 15, b = bh >> 4;
  const int r  = i >> 5, c = i & 31;

  const bf16* base = qkv + (size_t)(b * 1024) * 3072 + h * 64 + ch * 8;

  bf16x8_t qv = *reinterpret_cast<const bf16x8_t*>(base + (size_t)i * 3072);
  float qf[8];
#pragma unroll
  for (int e = 0; e < 8; ++e) qf[e] = (float)qv[e];

  float s[9];
  bool valid[9];
#pragma unroll
  for (int dr = -1; dr <= 1; ++dr) {
#pragma unroll
    for (int dc = -1; dc <= 1; ++dc) {
      const int idx = (dr + 1) * 3 + (dc + 1);
      const int rr = r + dr, cc = c + dc;
      valid[idx] = (rr >= 0 && rr < 32 && cc >= 0 && cc < 32);
      float sv = -1e30f;
      if (valid[idx]) {
        const int j = rr * 32 + cc;
        bf16x8_t kv = *reinterpret_cast<const bf16x8_t*>(base + (size_t)j * 3072 + 1024);
        float ps = 0.f;
#pragma unroll
        for (int e = 0; e < 8; ++e) ps += qf[e] * (float)kv[e];
        ps += __shfl_xor(ps, 1);
        ps += __shfl_xor(ps, 2);
        ps += __shfl_xor(ps, 4);
        sv = ps * 0.125f;
      }
      s[idx] = sv;
    }
  }

  float mx = s[0];
#pragma unroll
  for (int t = 1; t < 9; ++t) mx = fmaxf(mx, s[t]);

  float p[9], denom = 0.f;
#pragma unroll
  for (int t = 0; t < 9; ++t) {
    p[t] = valid[t] ? __expf(s[t] - mx) : 0.f;
    denom += p[t];
  }

  float o[8] = {};
#pragma unroll
  for (int dr = -1; dr <= 1; ++dr) {
#pragma unroll
    for (int dc = -1; dc <= 1; ++dc) {
      const int idx = (dr + 1) * 3 + (dc + 1);
      if (valid[idx]) {
        const int j = (r + dr) * 32 + (c + dc);
        bf16x8_t vv = *reinterpret_cast<const bf16x8_t*>(base + (size_t)j * 3072 + 2048);
        const float pw = p[idx];
#pragma unroll
        for (int e = 0; e < 8; ++e) o[e] += pw * (float)vv[e];
      }
    }
  }

  const float inv = 1.f / denom;
  bf16x8_t ov;
#pragma unroll
  for (int e = 0; e < 8; ++e) ov[e] = (bf16)(o[e] * inv);
  *reinterpret_cast<bf16x8_t*>(outp + (size_t)(b * 1024 + i) * 1024 + h * 64 + ch * 8) = ov;
}

extern "C" void kernel_launch(void* const* d_in, const int* in_sizes, int n_in,
                              void* d_out, int out_size, void* d_ws, size_t ws_size,
                              hipStream_t stream) {
  const float* x      = (const float*)d_in[0];
  const float* w_qkv  = (const float*)d_in[1];
  const float* w_proj = (const float*)d_in[2];
  const float* b_proj = (const float*)d_in[3];
  float* out = (float*)d_out;

  const size_t nx   = (size_t)16384 * 1024;
  const size_t nwq  = (size_t)3072 * 1024;
  const size_t nwp  = (size_t)1024 * 1024;
  const size_t nqkv = (size_t)16384 * 3072;

  bf16* x_bf  = (bf16*)d_ws;
  bf16* wq_bf = x_bf + nx;
  bf16* wp_bf = wq_bf + nwq;
  bf16* qkv   = wp_bf + nwp;
  bf16* attn  = qkv + nqkv;

  (void)hipFuncSetAttribute((const void*)&gemm8p<1>,
                            hipFuncAttributeMaxDynamicSharedMemorySize, 131072);
  (void)hipFuncSetAttribute((const void*)&gemm8p<0>,
                            hipFuncAttributeMaxDynamicSharedMemorySize, 131072);

  // fused cvt: (nx+nwq+nwp)/4 float4s = 5242880 -> 20480 blocks x 256
  cvt_all<<<20480, 256, 0, stream>>>(x, w_qkv, w_proj, x_bf, wq_bf, wp_bf);

  // qkv = x @ w_qkv^T : M=16384, N=3072, K=1024 ; grid 12x64=768 (%8==0)
  gemm8p<1><<<dim3(3072 / 256, 16384 / 256), 512, 131072, stream>>>(
      x_bf, wq_bf, qkv, nullptr, 16384, 3072, 1024);

  // local window attention: 262144 tokens, 32 tokens/block
  local_attn<<<8192, 256, 0, stream>>>(qkv, attn);

  // out = attn @ w_proj^T + b : M=16384, N=1024, K=1024 ; grid 4x64=256
  gemm8p<0><<<dim3(1024 / 256, 16384 / 256), 512, 131072, stream>>>(
      attn, wp_bf, out, b_proj, 16384, 1024, 1024);
}

// Round 10
// 212.983 us; speedup vs baseline: 1.4794x; 1.0193x over previous
//
#include <hip/hip_runtime.h>
#include <hip/hip_bf16.h>
#include <stdint.h>

// LocalAttention: B=16, N=1024 (32x32 grid), C=1024, H=16, D=64.
// cvt->bf16 (fused) ; GEMM1 qkv=x@w_qkv^T ; local 3x3 window attention ;
// GEMM2 out=attn@w_proj^T+b. Workspace ~176.2 MB.
//
// GEMM (round 10): zig-zag body (r4/r6, best measured) + 3-slot rotating LDS
// pipeline. BK=32, BM=BN=256, 8 waves. Staging tile kt+2 -> slot (kt+2)%3 !=
// current slot, so it issues at the TOP of the body (no pre-stage barrier):
// ONE barrier/tile (r6: 2) and the tile-end vmcnt(4) waits on loads issued a
// full extra body earlier. Hazard: slot s+2 last read in tile kt-1, certified
// by its end barrier; stage(kt+2) drained by end-of-(kt+1) vmcnt before read.
// Phase-split schedules rejected (3 attempts r3/r5/r9 all lost to this).

typedef __bf16 bf16;
typedef __bf16 bf16x4_t __attribute__((ext_vector_type(4)));
typedef __bf16 bf16x8_t __attribute__((ext_vector_type(8)));
typedef float f32x4_t __attribute__((ext_vector_type(4)));

static __device__ __forceinline__ void gload_lds16(const void* g, void* l) {
  __builtin_amdgcn_global_load_lds((__attribute__((address_space(1))) void*)g,
                                   (__attribute__((address_space(3))) void*)l,
                                   16, 0, 0);
}

// raw s_barrier with compile-time memory fences (no vmcnt/lgkm drain)
static __device__ __forceinline__ void block_barrier() {
  asm volatile("" ::: "memory");
  __builtin_amdgcn_s_barrier();
  asm volatile("" ::: "memory");
}

// ---------------- fused f32 -> bf16 conversion (x, w_qkv, w_proj) --------------
__global__ void cvt_all(const float* __restrict__ x, const float* __restrict__ wq,
                        const float* __restrict__ wp, bf16* __restrict__ xb,
                        bf16* __restrict__ wqb, bf16* __restrict__ wpb) {
  constexpr int NX = 4194304, NWQ = 786432;          // float4 counts
  int i = blockIdx.x * blockDim.x + threadIdx.x;     // grid exactly covers total
  const float* src; bf16* dst; int off;
  if (i < NX)            { src = x;  dst = xb;  off = i; }
  else if (i < NX + NWQ) { src = wq; dst = wqb; off = i - NX; }
  else                   { src = wp; dst = wpb; off = i - (NX + NWQ); }
  float4 v = reinterpret_cast<const float4*>(src)[off];
  bf16x4_t o;
  o[0] = (bf16)v.x; o[1] = (bf16)v.y; o[2] = (bf16)v.z; o[3] = (bf16)v.w;
  reinterpret_cast<bf16x4_t*>(dst)[off] = o;
}

// ---------------- 256x256 8-wave bf16 GEMM, C = A @ B^T, BK=32, 3-slot ---------
// A: [M][K], Bm: [N][K] (both K-major). 512 threads = 8 waves (2M x 4N).
// LDS: 3 slots x (A 256x32 + B 256x32) bf16 = 96 KiB. T2 swizzle as r6
// (verified: 0 bank conflicts, absmax pass).
template<int OUT_BF16>
__global__ __launch_bounds__(512, 2)
void gemm3s(const bf16* __restrict__ A, const bf16* __restrict__ Bm,
            void* __restrict__ Cout, const float* __restrict__ bias,
            int M, int N, int K) {
  constexpr int SLOT = 32768;                // A 16KB + B 16KB
  extern __shared__ __align__(16) char lds[];

  const int tid = threadIdx.x;
  const int w = tid >> 6, lane = tid & 63;
  const int fr = lane & 15, g = lane >> 4;
  const int wr = w >> 2, wc = w & 3;          // wave grid 2 x 4

  // T1: XCD-aware bijective swizzle (nwg % 8 == 0 for both call sites)
  const int nwg = gridDim.x * gridDim.y;
  int lid = blockIdx.y * gridDim.x + blockIdx.x;
  lid = (lid & 7) * (nwg >> 3) + (lid >> 3);
  const int bx = lid % gridDim.x, by = lid / gridDim.x;
  const int row0 = by * 256, col0 = bx * 256;

  const bf16* Ag = A + (size_t)row0 * K;
  const bf16* Bg = Bm + (size_t)col0 * K;
  const int srow = tid >> 2;                                // 0..127
  const int scol = ((tid & 3) ^ ((tid >> 3) & 3)) * 8;      // inverse-swizzled col
  const int nkt  = K >> 5;                                  // 32

  f32x4_t acc[8][4] = {};

  auto stage = [&](int kt, int slot) {
    const int kb = kt << 5;
    char* sb = lds + slot * SLOT;
    gload_lds16(Ag + (size_t)(srow) * K + kb + scol,       sb + tid * 16);
    gload_lds16(Ag + (size_t)(128 + srow) * K + kb + scol, sb + 8192 + tid * 16);
    gload_lds16(Bg + (size_t)(srow) * K + kb + scol,       sb + 16384 + tid * 16);
    gload_lds16(Bg + (size_t)(128 + srow) * K + kb + scol, sb + 24576 + tid * 16);
  };

  const int uxor = ((fr >> 1) & 3) << 4;   // T2 read-side XOR (lane-constant)

  // prologue: tiles 0,1 staged into slots 0,1; wait tile 0 (tile 1 in flight)
  stage(0, 0);
  stage(1, 1);
  asm volatile("s_waitcnt vmcnt(4)" ::: "memory");
  block_barrier();

  int sl = 0;   // slot of current tile
  for (int kt = 0; kt < nkt; ++kt) {
    const bool pf = (kt + 2 < nkt);
    int s2 = sl + 2; if (s2 >= 3) s2 -= 3;
    if (pf) stage(kt + 2, s2);               // top-of-body staging (slot free
                                             // since tile kt-1's end barrier)
    const char* cA = lds + sl * SLOT;
    const char* cB = cA + 16384;

    bf16x8_t a0[4], a1[4], b0[2], b1[2];
    auto lda = [&](bf16x8_t (&dst)[4], int q) {
#pragma unroll
      for (int i = 0; i < 4; ++i) {
        const int row = wr * 128 + (q * 4 + i) * 16 + fr;
        dst[i] = *reinterpret_cast<const bf16x8_t*>(cA + (row << 6) + ((g << 4) ^ uxor));
      }
    };
    auto ldb = [&](bf16x8_t (&dst)[2], int q) {
#pragma unroll
      for (int j = 0; j < 2; ++j) {
        const int row = wc * 64 + (q * 2 + j) * 16 + fr;
        dst[j] = *reinterpret_cast<const bf16x8_t*>(cB + (row << 6) + ((g << 4) ^ uxor));
      }
    };

    // zig-zag: each fragment read once; b0 held across the tile
    lda(a0, 0);
    ldb(b0, 0);
#pragma unroll
    for (int i = 0; i < 4; ++i)
#pragma unroll
      for (int j = 0; j < 2; ++j)
        acc[i][j] = __builtin_amdgcn_mfma_f32_16x16x32_bf16(a0[i], b0[j], acc[i][j], 0, 0, 0);
    ldb(b1, 1);
#pragma unroll
    for (int i = 0; i < 4; ++i)
#pragma unroll
      for (int j = 0; j < 2; ++j)
        acc[i][2 + j] = __builtin_amdgcn_mfma_f32_16x16x32_bf16(a0[i], b1[j], acc[i][2 + j], 0, 0, 0);
    lda(a1, 1);
#pragma unroll
    for (int i = 0; i < 4; ++i)
#pragma unroll
      for (int j = 0; j < 2; ++j)
        acc[4 + i][2 + j] = __builtin_amdgcn_mfma_f32_16x16x32_bf16(
            a1[i], b1[j], acc[4 + i][2 + j], 0, 0, 0);
#pragma unroll
    for (int i = 0; i < 4; ++i)
#pragma unroll
      for (int j = 0; j < 2; ++j)
        acc[4 + i][j] = __builtin_amdgcn_mfma_f32_16x16x32_bf16(
            a1[i], b0[j], acc[4 + i][j], 0, 0, 0);

    // wait tile kt+1 resident (leave the 4 loads staged this tile in flight)
    if (pf) asm volatile("s_waitcnt vmcnt(4)" ::: "memory");
    else    asm volatile("s_waitcnt vmcnt(0)" ::: "memory");
    block_barrier();
    sl = (sl + 1 == 3) ? 0 : sl + 1;
  }

  // epilogue: D row = g*4+r (M), col = fr (N) per verified m89 layout
#pragma unroll
  for (int fm = 0; fm < 8; ++fm) {
    const int rbase = row0 + wr * 128 + fm * 16 + g * 4;
#pragma unroll
    for (int fn = 0; fn < 4; ++fn) {
      const int col = col0 + wc * 64 + fn * 16 + fr;
#pragma unroll
      for (int r = 0; r < 4; ++r) {
        const size_t idx = (size_t)(rbase + r) * N + col;
        if constexpr (OUT_BF16) {
          reinterpret_cast<bf16*>(Cout)[idx] = (bf16)acc[fm][fn][r];
        } else {
          reinterpret_cast<float*>(Cout)[idx] = acc[fm][fn][r] + bias[col];
        }
      }
    }
  }
}

// ---------------- local 3x3 window attention -----------------------------------
// qkv: [B*N][3072] bf16 (q|k|v, head h at h*64). out: [B*N][1024] bf16.
// 8 tokens/wave, 8 lanes/token (16B d-chunk each). Branch-free: neighbor
// addresses clamped into range (invalid -> s=-1e30 -> exp=0). All 9 K rows
// then all 9 V rows prefetched into registers BEFORE the softmax chain --
// V latency hides under dots/softmax instead of serializing after it.
__global__ __launch_bounds__(256)
void local_attn(const bf16* __restrict__ qkv, bf16* __restrict__ outp) {
  const int tid  = threadIdx.x;
  const int wave = tid >> 6, lane = tid & 63;
  const int tsub = lane >> 3, ch = lane & 7;
  const int gt = (blockIdx.x * 4 + wave) * 8 + tsub;
  const int i  = gt & 1023;
  const int bh = gt >> 10;
  const int h  = bh & 15, b = bh >> 4;
  const int r  = i >> 5, c = i & 31;

  const bf16* base = qkv + (size_t)(b * 1024) * 3072 + h * 64 + ch * 8;

  bf16x8_t qv = *reinterpret_cast<const bf16x8_t*>(base + (size_t)i * 3072);
  float qf[8];
#pragma unroll
  for (int e = 0; e < 8; ++e) qf[e] = (float)qv[e];

  // clamped neighbor indices + validity mask (no branches)
  int jj[9]; float inval[9];
#pragma unroll
  for (int t = 0; t < 9; ++t) {
    const int dr = t / 3 - 1, dc = t % 3 - 1;
    const int rr = r + dr, cc = c + dc;
    const int rcl = min(max(rr, 0), 31), ccl = min(max(cc, 0), 31);
    jj[t] = rcl * 32 + ccl;
    inval[t] = (rr == rcl && cc == ccl) ? 0.f : -1e30f;
  }

  // prefetch all K rows, then all V rows (36+36 VGPR, issued before any dot)
  bf16x8_t kv[9], vv[9];
#pragma unroll
  for (int t = 0; t < 9; ++t)
    kv[t] = *reinterpret_cast<const bf16x8_t*>(base + (size_t)jj[t] * 3072 + 1024);
#pragma unroll
  for (int t = 0; t < 9; ++t)
    vv[t] = *reinterpret_cast<const bf16x8_t*>(base + (size_t)jj[t] * 3072 + 2048);

  float s[9];
#pragma unroll
  for (int t = 0; t < 9; ++t) {
    float ps = 0.f;
#pragma unroll
    for (int e = 0; e < 8; ++e) ps += qf[e] * (float)kv[t][e];
    ps += __shfl_xor(ps, 1);
    ps += __shfl_xor(ps, 2);
    ps += __shfl_xor(ps, 4);
    s[t] = ps * 0.125f + inval[t];   // invalid -> -1e30
  }

  float mx = s[0];
#pragma unroll
  for (int t = 1; t < 9; ++t) mx = fmaxf(mx, s[t]);

  float denom = 0.f, o[8] = {};
#pragma unroll
  for (int t = 0; t < 9; ++t) {
    const float p = __expf(s[t] - mx);   // exp(-huge)=0 for invalid
    denom += p;
#pragma unroll
    for (int e = 0; e < 8; ++e) o[e] += p * (float)vv[t][e];
  }

  const float inv = 1.f / denom;
  bf16x8_t ov;
#pragma unroll
  for (int e = 0; e < 8; ++e) ov[e] = (bf16)(o[e] * inv);
  *reinterpret_cast<bf16x8_t*>(outp + (size_t)(b * 1024 + i) * 1024 + h * 64 + ch * 8) = ov;
}

extern "C" void kernel_launch(void* const* d_in, const int* in_sizes, int n_in,
                              void* d_out, int out_size, void* d_ws, size_t ws_size,
                              hipStream_t stream) {
  const float* x      = (const float*)d_in[0];
  const float* w_qkv  = (const float*)d_in[1];
  const float* w_proj = (const float*)d_in[2];
  const float* b_proj = (const float*)d_in[3];
  float* out = (float*)d_out;

  const size_t nx   = (size_t)16384 * 1024;
  const size_t nwq  = (size_t)3072 * 1024;
  const size_t nwp  = (size_t)1024 * 1024;
  const size_t nqkv = (size_t)16384 * 3072;

  bf16* x_bf  = (bf16*)d_ws;
  bf16* wq_bf = x_bf + nx;
  bf16* wp_bf = wq_bf + nwq;
  bf16* qkv   = wp_bf + nwp;
  bf16* attn  = qkv + nqkv;

  (void)hipFuncSetAttribute((const void*)&gemm3s<1>,
                            hipFuncAttributeMaxDynamicSharedMemorySize, 98304);
  (void)hipFuncSetAttribute((const void*)&gemm3s<0>,
                            hipFuncAttributeMaxDynamicSharedMemorySize, 98304);

  // fused cvt: (nx+nwq+nwp)/4 float4s = 5242880 -> 20480 blocks x 256
  cvt_all<<<20480, 256, 0, stream>>>(x, w_qkv, w_proj, x_bf, wq_bf, wp_bf);

  // qkv = x @ w_qkv^T : M=16384, N=3072, K=1024 ; grid 12x64=768 (%8==0)
  gemm3s<1><<<dim3(3072 / 256, 16384 / 256), 512, 98304, stream>>>(
      x_bf, wq_bf, qkv, nullptr, 16384, 3072, 1024);

  // local window attention: 262144 tokens, 32 tokens/block
  local_attn<<<8192, 256, 0, stream>>>(qkv, attn);

  // out = attn @ w_proj^T + b : M=16384, N=1024, K=1024 ; grid 4x64=256 (%8==0)
  gemm3s<0><<<dim3(1024 / 256, 16384 / 256), 512, 98304, stream>>>(
      attn, wp_bf, out, b_proj, 16384, 1024, 1024);
}

// Round 11
// 212.751 us; speedup vs baseline: 1.4810x; 1.0011x over previous
//
#include <hip/hip_runtime.h>
#include <hip/hip_bf16.h>
#include <stdint.h>

// LocalAttention: B=16, N=1024 (32x32 grid), C=1024, H=16, D=64.
// cvt->bf16 (fused) ; GEMM1 qkv=x@w_qkv^T ; local 3x3 window attention (LDS
// window staging) ; GEMM2 out=attn@w_proj^T+b. Workspace ~176.2 MB.
//
// GEMM (round 11): 4-wave 256-thread blocks, tile 256x128, wave 128x64, BK=32,
// 3-slot rotating LDS (72 KiB). Per-wave regs ~200 <= 256 -> TWO blocks/CU
// co-resident (fixes r6's register blocker at 512-thr blocks): block A's MFMA
// overlaps block B's LDS/stage phases (m114 mechanism). LDS amplification
// drops 96->48 KB reads per 256x256-equivalent tile. Body/swizzle/vmcnt
// discipline identical to r10 (verified: 0 conflicts, absmax pass).

typedef __bf16 bf16;
typedef __bf16 bf16x4_t __attribute__((ext_vector_type(4)));
typedef __bf16 bf16x8_t __attribute__((ext_vector_type(8)));
typedef float f32x4_t __attribute__((ext_vector_type(4)));

static __device__ __forceinline__ void gload_lds16(const void* g, void* l) {
  __builtin_amdgcn_global_load_lds((__attribute__((address_space(1))) void*)g,
                                   (__attribute__((address_space(3))) void*)l,
                                   16, 0, 0);
}

// raw s_barrier with compile-time memory fences (no vmcnt/lgkm drain)
static __device__ __forceinline__ void block_barrier() {
  asm volatile("" ::: "memory");
  __builtin_amdgcn_s_barrier();
  asm volatile("" ::: "memory");
}

// ---------------- fused f32 -> bf16 conversion (x, w_qkv, w_proj) --------------
__global__ void cvt_all(const float* __restrict__ x, const float* __restrict__ wq,
                        const float* __restrict__ wp, bf16* __restrict__ xb,
                        bf16* __restrict__ wqb, bf16* __restrict__ wpb) {
  constexpr int NX = 4194304, NWQ = 786432;          // float4 counts
  int i = blockIdx.x * blockDim.x + threadIdx.x;     // grid exactly covers total
  const float* src; bf16* dst; int off;
  if (i < NX)            { src = x;  dst = xb;  off = i; }
  else if (i < NX + NWQ) { src = wq; dst = wqb; off = i - NX; }
  else                   { src = wp; dst = wpb; off = i - (NX + NWQ); }
  float4 v = reinterpret_cast<const float4*>(src)[off];
  bf16x4_t o;
  o[0] = (bf16)v.x; o[1] = (bf16)v.y; o[2] = (bf16)v.z; o[3] = (bf16)v.w;
  reinterpret_cast<bf16x4_t*>(dst)[off] = o;
}

// ---------------- 256x128 4-wave bf16 GEMM, C = A @ B^T, BK=32, 3-slot ---------
// A: [M][K], Bm: [N][K] (both K-major). 256 threads = 4 waves (2M x 2N),
// wave tile 128x64. LDS: 3 slots x (A 256x32 + B 128x32) bf16 = 72 KiB.
template<int OUT_BF16>
__global__ __launch_bounds__(256, 2)
void gemm4w(const bf16* __restrict__ A, const bf16* __restrict__ Bm,
            void* __restrict__ Cout, const float* __restrict__ bias,
            int M, int N, int K) {
  constexpr int SLOT = 24576;                // A 16KB + B 8KB
  extern __shared__ __align__(16) char lds[];

  const int tid = threadIdx.x;
  const int w = tid >> 6, lane = tid & 63;
  const int fr = lane & 15, g = lane >> 4;
  const int wr = w >> 1, wc = w & 1;          // wave grid 2 x 2

  // T1: XCD-aware bijective swizzle (nwg % 8 == 0 for both call sites)
  const int nwg = gridDim.x * gridDim.y;
  int lid = blockIdx.y * gridDim.x + blockIdx.x;
  lid = (lid & 7) * (nwg >> 3) + (lid >> 3);
  const int bx = lid % gridDim.x, by = lid / gridDim.x;
  const int row0 = by * 256, col0 = bx * 128;

  const bf16* Ag = A + (size_t)row0 * K;
  const bf16* Bg = Bm + (size_t)col0 * K;
  const int srow = tid >> 2;                                // 0..63
  const int scol = ((tid & 3) ^ ((tid >> 3) & 3)) * 8;      // inverse-swizzled col
  const int nkt  = K >> 5;                                  // 32

  f32x4_t acc[8][4] = {};

  auto stage = [&](int kt, int slot) {     // 6 gload_lds16 per thread
    const int kb = kt << 5;
    char* sb = lds + slot * SLOT;
#pragma unroll
    for (int n = 0; n < 4; ++n)            // A: 256 rows x 32 cols
      gload_lds16(Ag + (size_t)(n * 64 + srow) * K + kb + scol,
                  sb + n * 4096 + tid * 16);
#pragma unroll
    for (int n = 0; n < 2; ++n)            // B: 128 rows x 32 cols
      gload_lds16(Bg + (size_t)(n * 64 + srow) * K + kb + scol,
                  sb + 16384 + n * 4096 + tid * 16);
  };

  const int uxor = ((fr >> 1) & 3) << 4;   // T2 read-side XOR (lane-constant)

  // prologue: tiles 0,1 staged into slots 0,1; wait tile 0 (tile 1 in flight)
  stage(0, 0);
  stage(1, 1);
  asm volatile("s_waitcnt vmcnt(6)" ::: "memory");
  block_barrier();

  int sl = 0;   // slot of current tile
  for (int kt = 0; kt < nkt; ++kt) {
    const bool pf = (kt + 2 < nkt);
    int s2 = sl + 2; if (s2 >= 3) s2 -= 3;
    if (pf) stage(kt + 2, s2);               // top-of-body staging (slot free
                                             // since tile kt-1's end barrier)
    const char* cA = lds + sl * SLOT;
    const char* cB = cA + 16384;

    bf16x8_t a0[4], a1[4], b0[2], b1[2];
    auto lda = [&](bf16x8_t (&dst)[4], int q) {
#pragma unroll
      for (int i = 0; i < 4; ++i) {
        const int row = wr * 128 + (q * 4 + i) * 16 + fr;
        dst[i] = *reinterpret_cast<const bf16x8_t*>(cA + (row << 6) + ((g << 4) ^ uxor));
      }
    };
    auto ldb = [&](bf16x8_t (&dst)[2], int q) {
#pragma unroll
      for (int j = 0; j < 2; ++j) {
        const int row = wc * 64 + (q * 2 + j) * 16 + fr;
        dst[j] = *reinterpret_cast<const bf16x8_t*>(cB + (row << 6) + ((g << 4) ^ uxor));
      }
    };

    // zig-zag: each fragment read once; b0 held across the tile
    lda(a0, 0);
    ldb(b0, 0);
#pragma unroll
    for (int i = 0; i < 4; ++i)
#pragma unroll
      for (int j = 0; j < 2; ++j)
        acc[i][j] = __builtin_amdgcn_mfma_f32_16x16x32_bf16(a0[i], b0[j], acc[i][j], 0, 0, 0);
    ldb(b1, 1);
#pragma unroll
    for (int i = 0; i < 4; ++i)
#pragma unroll
      for (int j = 0; j < 2; ++j)
        acc[i][2 + j] = __builtin_amdgcn_mfma_f32_16x16x32_bf16(a0[i], b1[j], acc[i][2 + j], 0, 0, 0);
    lda(a1, 1);
#pragma unroll
    for (int i = 0; i < 4; ++i)
#pragma unroll
      for (int j = 0; j < 2; ++j)
        acc[4 + i][2 + j] = __builtin_amdgcn_mfma_f32_16x16x32_bf16(
            a1[i], b1[j], acc[4 + i][2 + j], 0, 0, 0);
#pragma unroll
    for (int i = 0; i < 4; ++i)
#pragma unroll
      for (int j = 0; j < 2; ++j)
        acc[4 + i][j] = __builtin_amdgcn_mfma_f32_16x16x32_bf16(
            a1[i], b0[j], acc[4 + i][j], 0, 0, 0);

    // wait tile kt+1 resident (leave the 6 loads staged this tile in flight)
    if (pf) asm volatile("s_waitcnt vmcnt(6)" ::: "memory");
    else    asm volatile("s_waitcnt vmcnt(0)" ::: "memory");
    block_barrier();
    sl = (sl + 1 == 3) ? 0 : sl + 1;
  }

  // epilogue: D row = g*4+r (M), col = fr (N) per verified m89 layout
#pragma unroll
  for (int fm = 0; fm < 8; ++fm) {
    const int rbase = row0 + wr * 128 + fm * 16 + g * 4;
#pragma unroll
    for (int fn = 0; fn < 4; ++fn) {
      const int col = col0 + wc * 64 + fn * 16 + fr;
#pragma unroll
      for (int r = 0; r < 4; ++r) {
        const size_t idx = (size_t)(rbase + r) * N + col;
        if constexpr (OUT_BF16) {
          reinterpret_cast<bf16*>(Cout)[idx] = (bf16)acc[fm][fn][r];
        } else {
          reinterpret_cast<float*>(Cout)[idx] = acc[fm][fn][r] + bias[col];
        }
      }
    }
  }
}

// ---------------- local 3x3 window attention (LDS window staging) --------------
// qkv: [B*N][3072] bf16 (q|k|v, head h at h*64). out: [B*N][1024] bf16.
// Block = (b, h, grid-row r): 32 tokens, 256 threads (8 lanes/token, 8 dims ea).
// Stage the 3x32-token K and V window (rows r-1..r+1, clamped) into LDS once
// via global_load_lds (linear dest), then all 9 dots + PV read LDS. Global
// loads/thread: 19 -> 7. 128B-row layout => every wave b128 read lands 8 words
// on each bank (uniform = conflict-minimal).
__global__ __launch_bounds__(256)
void local_attn(const bf16* __restrict__ qkv, bf16* __restrict__ outp) {
  __shared__ __align__(16) char sK[12288];   // [96][64] bf16
  __shared__ __align__(16) char sV[12288];

  const int tid  = threadIdx.x;
  const int w = tid >> 6, lane = tid & 63;
  const int ch = lane & 7;
  const int bid = blockIdx.x;                // 8192 = 16 B x 16 H x 32 rows
  const int r = bid & 31, h = (bid >> 5) & 15, b = bid >> 9;

  const bf16* qkvb = qkv + (size_t)(b * 1024) * 3072 + h * 64;
  const int tokp = w * 8 + (lane >> 3);      // token column 0..31

  // stage K and V windows: pass u covers window row u (grid row r-1+u clamped)
#pragma unroll
  for (int u = 0; u < 3; ++u) {
    const int jrow = min(max(r - 1 + u, 0), 31);
    const size_t j = (size_t)(jrow * 32 + tokp);
    gload_lds16(qkvb + j * 3072 + 1024 + ch * 8, sK + u * 4096 + w * 1024 + (lane & 7) * 16 + (lane >> 3) * 128);
  }
#pragma unroll
  for (int u = 0; u < 3; ++u) {
    const int jrow = min(max(r - 1 + u, 0), 31);
    const size_t j = (size_t)(jrow * 32 + tokp);
    gload_lds16(qkvb + j * 3072 + 2048 + ch * 8, sV + u * 4096 + w * 1024 + (lane & 7) * 16 + (lane >> 3) * 128);
  }

  // q for this thread's token/chunk (overlaps with staging)
  const int c = tokp, i = r * 32 + c;
  bf16x8_t qv = *reinterpret_cast<const bf16x8_t*>(qkvb + (size_t)i * 3072 + ch * 8);
  float qf[8];
#pragma unroll
  for (int e = 0; e < 8; ++e) qf[e] = (float)qv[e];

  __syncthreads();   // staging complete (drains vmcnt)

  float s[9];
#pragma unroll
  for (int t = 0; t < 9; ++t) {
    const int dr = t / 3 - 1, dc = t % 3 - 1;
    const int rr = r + dr, cc = c + dc;
    const int ccl = min(max(cc, 0), 31);
    const int wtok = (dr + 1) * 32 + ccl;
    const bf16x8_t kvv = *reinterpret_cast<const bf16x8_t*>(sK + wtok * 128 + ch * 16);
    float ps = 0.f;
#pragma unroll
    for (int e = 0; e < 8; ++e) ps += qf[e] * (float)kvv[e];
    ps += __shfl_xor(ps, 1);
    ps += __shfl_xor(ps, 2);
    ps += __shfl_xor(ps, 4);
    const bool valid = (rr >= 0 && rr < 32 && cc >= 0 && cc < 32);
    s[t] = ps * 0.125f + (valid ? 0.f : -1e30f);
  }

  float mx = s[0];
#pragma unroll
  for (int t = 1; t < 9; ++t) mx = fmaxf(mx, s[t]);

  float denom = 0.f, o[8] = {};
#pragma unroll
  for (int t = 0; t < 9; ++t) {
    const int dr = t / 3 - 1, dc = t % 3 - 1;
    const int ccl = min(max(c + dc, 0), 31);
    const int wtok = (dr + 1) * 32 + ccl;
    const float p = __expf(s[t] - mx);       // exp(-huge)=0 for invalid
    denom += p;
    const bf16x8_t vvv = *reinterpret_cast<const bf16x8_t*>(sV + wtok * 128 + ch * 16);
#pragma unroll
    for (int e = 0; e < 8; ++e) o[e] += p * (float)vvv[e];
  }

  const float inv = 1.f / denom;
  bf16x8_t ov;
#pragma unroll
  for (int e = 0; e < 8; ++e) ov[e] = (bf16)(o[e] * inv);
  *reinterpret_cast<bf16x8_t*>(outp + (size_t)(b * 1024 + i) * 1024 + h * 64 + ch * 8) = ov;
}

extern "C" void kernel_launch(void* const* d_in, const int* in_sizes, int n_in,
                              void* d_out, int out_size, void* d_ws, size_t ws_size,
                              hipStream_t stream) {
  const float* x      = (const float*)d_in[0];
  const float* w_qkv  = (const float*)d_in[1];
  const float* w_proj = (const float*)d_in[2];
  const float* b_proj = (const float*)d_in[3];
  float* out = (float*)d_out;

  const size_t nx   = (size_t)16384 * 1024;
  const size_t nwq  = (size_t)3072 * 1024;
  const size_t nwp  = (size_t)1024 * 1024;
  const size_t nqkv = (size_t)16384 * 3072;

  bf16* x_bf  = (bf16*)d_ws;
  bf16* wq_bf = x_bf + nx;
  bf16* wp_bf = wq_bf + nwq;
  bf16* qkv   = wp_bf + nwp;
  bf16* attn  = qkv + nqkv;

  (void)hipFuncSetAttribute((const void*)&gemm4w<1>,
                            hipFuncAttributeMaxDynamicSharedMemorySize, 73728);
  (void)hipFuncSetAttribute((const void*)&gemm4w<0>,
                            hipFuncAttributeMaxDynamicSharedMemorySize, 73728);

  // fused cvt: (nx+nwq+nwp)/4 float4s = 5242880 -> 20480 blocks x 256
  cvt_all<<<20480, 256, 0, stream>>>(x, w_qkv, w_proj, x_bf, wq_bf, wp_bf);

  // qkv = x @ w_qkv^T : M=16384, N=3072, K=1024 ; grid 24x64=1536 (%8==0)
  gemm4w<1><<<dim3(3072 / 128, 16384 / 256), 256, 73728, stream>>>(
      x_bf, wq_bf, qkv, nullptr, 16384, 3072, 1024);

  // local window attention: 8192 blocks x 256 thr (one (b,h,row) per block)
  local_attn<<<8192, 256, 0, stream>>>(qkv, attn);

  // out = attn @ w_proj^T + b : M=16384, N=1024, K=1024 ; grid 8x64=512 (%8==0)
  gemm4w<0><<<dim3(1024 / 128, 16384 / 256), 256, 73728, stream>>>(
      attn, wp_bf, out, b_proj, 16384, 1024, 1024);
}

// Round 12
// 209.050 us; speedup vs baseline: 1.5073x; 1.0177x over previous
//
#include <hip/hip_runtime.h>
#include <hip/hip_bf16.h>
#include <stdint.h>

// LocalAttention: B=16, N=1024 (32x32 grid), C=1024, H=16, D=64.
// cvt->bf16 (fused) ; GEMM1 qkv=x@w_qkv^T (r6 gemm_bk32, best measured 112.4us,
// 874 TF) ; local 3x3 window attention (LDS window staging + DPP quad_perm
// reduce) ; GEMM2 out=attn@w_proj^T+b (same kernel, 256^2). Workspace ~176 MB.
//
// GEMM plateau accepted: 8 structural variants (BK32/64, 2/3/4-slot, 4/8-wave,
// phase-split x3, B-in-regs) all land 112-124us => ~874 TF m97-class wall.
// This round: best-variant assembly + attention DS-pipe reduction.

typedef __bf16 bf16;
typedef __bf16 bf16x4_t __attribute__((ext_vector_type(4)));
typedef __bf16 bf16x8_t __attribute__((ext_vector_type(8)));
typedef float f32x4_t __attribute__((ext_vector_type(4)));

static __device__ __forceinline__ void gload_lds16(const void* g, void* l) {
  __builtin_amdgcn_global_load_lds((__attribute__((address_space(1))) void*)g,
                                   (__attribute__((address_space(3))) void*)l,
                                   16, 0, 0);
}

// raw s_barrier with compile-time memory fences (no vmcnt/lgkm drain)
static __device__ __forceinline__ void block_barrier() {
  asm volatile("" ::: "memory");
  __builtin_amdgcn_s_barrier();
  asm volatile("" ::: "memory");
}

// lane-group add via DPP quad_perm (VALU pipe -- no DS op).
// CTRL 0xB1 = quad_perm[1,0,3,2] (xor 1); 0x4E = quad_perm[2,3,0,1] (xor 2).
template<int CTRL>
static __device__ __forceinline__ float dpp_xor_add(float v) {
  int x = __builtin_amdgcn_update_dpp(0, __float_as_int(v), CTRL, 0xF, 0xF, true);
  return v + __int_as_float(x);
}

// ---------------- fused f32 -> bf16 conversion (x, w_qkv, w_proj) --------------
__global__ void cvt_all(const float* __restrict__ x, const float* __restrict__ wq,
                        const float* __restrict__ wp, bf16* __restrict__ xb,
                        bf16* __restrict__ wqb, bf16* __restrict__ wpb) {
  constexpr int NX = 4194304, NWQ = 786432;          // float4 counts
  int i = blockIdx.x * blockDim.x + threadIdx.x;     // grid exactly covers total
  const float* src; bf16* dst; int off;
  if (i < NX)            { src = x;  dst = xb;  off = i; }
  else if (i < NX + NWQ) { src = wq; dst = wqb; off = i - NX; }
  else                   { src = wp; dst = wpb; off = i - (NX + NWQ); }
  float4 v = reinterpret_cast<const float4*>(src)[off];
  bf16x4_t o;
  o[0] = (bf16)v.x; o[1] = (bf16)v.y; o[2] = (bf16)v.z; o[3] = (bf16)v.w;
  reinterpret_cast<bf16x4_t*>(dst)[off] = o;
}

// ---------------- 256x256 8-wave bf16 GEMM, C = A @ B^T, BK=32 (r6 verbatim) ---
// A: [M][K], Bm: [N][K] (both K-major). 512 threads = 8 waves (2M x 4N).
// LDS: 2 slots x (A 256x32 + B 256x32) bf16 = 64 KiB. T2 swizzle (0 conflicts
// measured r6). Zig-zag body, each fragment read once, 2-deep staging,
// counted vmcnt (never drains in main loop). Best measured: 112.4us GEMM1.
template<int OUT_BF16>
__global__ __launch_bounds__(512, 2)
void gemm_bk32(const bf16* __restrict__ A, const bf16* __restrict__ Bm,
               void* __restrict__ Cout, const float* __restrict__ bias,
               int M, int N, int K) {
  constexpr int SLOT = 32768;                // A 16KB + B 16KB
  extern __shared__ __align__(16) char lds[];

  const int tid = threadIdx.x;
  const int w = tid >> 6, lane = tid & 63;
  const int fr = lane & 15, g = lane >> 4;
  const int wr = w >> 2, wc = w & 3;          // wave grid 2 x 4

  // T1: XCD-aware bijective swizzle (nwg % 8 == 0 for both call sites)
  const int nwg = gridDim.x * gridDim.y;
  int lid = blockIdx.y * gridDim.x + blockIdx.x;
  lid = (lid & 7) * (nwg >> 3) + (lid >> 3);
  const int bx = lid % gridDim.x, by = lid / gridDim.x;
  const int row0 = by * 256, col0 = bx * 256;

  const bf16* Ag = A + (size_t)row0 * K;
  const bf16* Bg = Bm + (size_t)col0 * K;
  const int srow = tid >> 2;                                // 0..127
  const int scol = ((tid & 3) ^ ((tid >> 3) & 3)) * 8;      // inverse-swizzled col
  const int nkt  = K >> 5;                                  // 32

  f32x4_t acc[8][4] = {};

  auto stage = [&](int kt, int slot) {       // 4 gload_lds16 per thread
    const int kb = kt << 5;
    char* sb = lds + slot * SLOT;
    gload_lds16(Ag + (size_t)(srow) * K + kb + scol,       sb + tid * 16);
    gload_lds16(Ag + (size_t)(128 + srow) * K + kb + scol, sb + 8192 + tid * 16);
    gload_lds16(Bg + (size_t)(srow) * K + kb + scol,       sb + 16384 + tid * 16);
    gload_lds16(Bg + (size_t)(128 + srow) * K + kb + scol, sb + 24576 + tid * 16);
  };

  const int uxor = ((fr >> 1) & 3) << 4;   // T2 read-side XOR (lane-constant)

  // prologue: tiles 0,1 staged; wait tile 0 (tile 1's 4 loads stay in flight)
  stage(0, 0);
  stage(1, 1);
  asm volatile("s_waitcnt vmcnt(4)" ::: "memory");
  block_barrier();

  for (int kt = 0; kt < nkt; ++kt) {
    const char* cA = lds + (kt & 1) * SLOT;
    const char* cB = cA + 16384;
    const bool pf = (kt + 2 < nkt);

    bf16x8_t a0[4], a1[4], b0[2], b1[2];
    auto lda = [&](bf16x8_t (&dst)[4], int q) {
#pragma unroll
      for (int i = 0; i < 4; ++i) {
        const int row = wr * 128 + (q * 4 + i) * 16 + fr;
        dst[i] = *reinterpret_cast<const bf16x8_t*>(cA + (row << 6) + ((g << 4) ^ uxor));
      }
    };
    auto ldb = [&](bf16x8_t (&dst)[2], int q) {
#pragma unroll
      for (int j = 0; j < 2; ++j) {
        const int row = wc * 64 + (q * 2 + j) * 16 + fr;
        dst[j] = *reinterpret_cast<const bf16x8_t*>(cB + (row << 6) + ((g << 4) ^ uxor));
      }
    };

    // zig-zag: each fragment read once; b0 held across the tile
    lda(a0, 0);
    ldb(b0, 0);
#pragma unroll
    for (int i = 0; i < 4; ++i)
#pragma unroll
      for (int j = 0; j < 2; ++j)
        acc[i][j] = __builtin_amdgcn_mfma_f32_16x16x32_bf16(a0[i], b0[j], acc[i][j], 0, 0, 0);
    ldb(b1, 1);
#pragma unroll
    for (int i = 0; i < 4; ++i)
#pragma unroll
      for (int j = 0; j < 2; ++j)
        acc[i][2 + j] = __builtin_amdgcn_mfma_f32_16x16x32_bf16(a0[i], b1[j], acc[i][2 + j], 0, 0, 0);
    lda(a1, 1);
#pragma unroll
    for (int i = 0; i < 4; ++i)
#pragma unroll
      for (int j = 0; j < 2; ++j)
        acc[4 + i][2 + j] = __builtin_amdgcn_mfma_f32_16x16x32_bf16(
            a1[i], b1[j], acc[4 + i][2 + j], 0, 0, 0);
#pragma unroll
    for (int i = 0; i < 4; ++i)
#pragma unroll
      for (int j = 0; j < 2; ++j)
        acc[4 + i][j] = __builtin_amdgcn_mfma_f32_16x16x32_bf16(
            a1[i], b0[j], acc[4 + i][j], 0, 0, 0);

    // every wave's ds_reads of this slot consumed above -> slot free after bar
    block_barrier();
    if (pf) stage(kt + 2, kt & 1);
    if (kt < nkt - 2) asm volatile("s_waitcnt vmcnt(4)" ::: "memory");
    else              asm volatile("s_waitcnt vmcnt(0)" ::: "memory");
    block_barrier();
  }

  // epilogue: D row = g*4+r (M), col = fr (N) per verified m89 layout
#pragma unroll
  for (int fm = 0; fm < 8; ++fm) {
    const int rbase = row0 + wr * 128 + fm * 16 + g * 4;
#pragma unroll
    for (int fn = 0; fn < 4; ++fn) {
      const int col = col0 + wc * 64 + fn * 16 + fr;
#pragma unroll
      for (int r = 0; r < 4; ++r) {
        const size_t idx = (size_t)(rbase + r) * N + col;
        if constexpr (OUT_BF16) {
          reinterpret_cast<bf16*>(Cout)[idx] = (bf16)acc[fm][fn][r];
        } else {
          reinterpret_cast<float*>(Cout)[idx] = acc[fm][fn][r] + bias[col];
        }
      }
    }
  }
}

// ---------------- local 3x3 window attention (LDS staging + DPP reduce) --------
// qkv: [B*N][3072] bf16 (q|k|v, head h at h*64). out: [B*N][1024] bf16.
// Block = (b, h, grid-row r): 32 tokens, 256 threads (8 lanes/token, 8 dims).
// K/V 3x32-token window staged to LDS once; 8-lane dot reduce = 2 DPP
// quad_perm adds (VALU pipe) + 1 shfl_xor(4) (DS) -- cross-lane DS ops per
// token drop 27 -> 9, cutting the block's DS-serial time ~40%.
__global__ __launch_bounds__(256)
void local_attn(const bf16* __restrict__ qkv, bf16* __restrict__ outp) {
  __shared__ __align__(16) char sK[12288];   // [96 tokens][64 bf16]
  __shared__ __align__(16) char sV[12288];

  const int tid  = threadIdx.x;
  const int w = tid >> 6, lane = tid & 63;
  const int ch = lane & 7;
  const int bid = blockIdx.x;                // 8192 = 16 B x 16 H x 32 rows
  const int r = bid & 31, h = (bid >> 5) & 15, b = bid >> 9;

  const bf16* qkvb = qkv + (size_t)(b * 1024) * 3072 + h * 64;
  const int tokp = w * 8 + (lane >> 3);      // token column 0..31

  // stage K and V windows: pass u covers window row u (grid row r-1+u clamped)
#pragma unroll
  for (int u = 0; u < 3; ++u) {
    const int jrow = min(max(r - 1 + u, 0), 31);
    const size_t j = (size_t)(jrow * 32 + tokp);
    gload_lds16(qkvb + j * 3072 + 1024 + ch * 8,
                sK + u * 4096 + w * 1024 + (lane & 7) * 16 + (lane >> 3) * 128);
  }
#pragma unroll
  for (int u = 0; u < 3; ++u) {
    const int jrow = min(max(r - 1 + u, 0), 31);
    const size_t j = (size_t)(jrow * 32 + tokp);
    gload_lds16(qkvb + j * 3072 + 2048 + ch * 8,
                sV + u * 4096 + w * 1024 + (lane & 7) * 16 + (lane >> 3) * 128);
  }

  // q for this thread's token/chunk (overlaps with staging)
  const int c = tokp, i = r * 32 + c;
  bf16x8_t qv = *reinterpret_cast<const bf16x8_t*>(qkvb + (size_t)i * 3072 + ch * 8);
  float qf[8];
#pragma unroll
  for (int e = 0; e < 8; ++e) qf[e] = (float)qv[e];

  __syncthreads();   // staging complete (drains vmcnt)

  float s[9];
#pragma unroll
  for (int t = 0; t < 9; ++t) {
    const int dr = t / 3 - 1, dc = t % 3 - 1;
    const int rr = r + dr, cc = c + dc;
    const int ccl = min(max(cc, 0), 31);
    const int wtok = (dr + 1) * 32 + ccl;
    const bf16x8_t kvv = *reinterpret_cast<const bf16x8_t*>(sK + wtok * 128 + ch * 16);
    float ps = 0.f;
#pragma unroll
    for (int e = 0; e < 8; ++e) ps += qf[e] * (float)kvv[e];
    ps = dpp_xor_add<0xB1>(ps);        // xor 1 (quad_perm, VALU)
    ps = dpp_xor_add<0x4E>(ps);        // xor 2 (quad_perm, VALU)
    ps += __shfl_xor(ps, 4);           // xor 4 (DS)
    const bool valid = (rr >= 0 && rr < 32 && cc >= 0 && cc < 32);
    s[t] = ps * 0.125f + (valid ? 0.f : -1e30f);
  }

  float mx = s[0];
#pragma unroll
  for (int t = 1; t < 9; ++t) mx = fmaxf(mx, s[t]);

  float denom = 0.f, o[8] = {};
#pragma unroll
  for (int t = 0; t < 9; ++t) {
    const int dr = t / 3 - 1, dc = t % 3 - 1;
    const int ccl = min(max(c + dc, 0), 31);
    const int wtok = (dr + 1) * 32 + ccl;
    const float p = __expf(s[t] - mx);       // exp(-huge)=0 for invalid
    denom += p;
    const bf16x8_t vvv = *reinterpret_cast<const bf16x8_t*>(sV + wtok * 128 + ch * 16);
#pragma unroll
    for (int e = 0; e < 8; ++e) o[e] += p * (float)vvv[e];
  }

  const float inv = 1.f / denom;
  bf16x8_t ov;
#pragma unroll
  for (int e = 0; e < 8; ++e) ov[e] = (bf16)(o[e] * inv);
  *reinterpret_cast<bf16x8_t*>(outp + (size_t)(b * 1024 + i) * 1024 + h * 64 + ch * 8) = ov;
}

extern "C" void kernel_launch(void* const* d_in, const int* in_sizes, int n_in,
                              void* d_out, int out_size, void* d_ws, size_t ws_size,
                              hipStream_t stream) {
  const float* x      = (const float*)d_in[0];
  const float* w_qkv  = (const float*)d_in[1];
  const float* w_proj = (const float*)d_in[2];
  const float* b_proj = (const float*)d_in[3];
  float* out = (float*)d_out;

  const size_t nx   = (size_t)16384 * 1024;
  const size_t nwq  = (size_t)3072 * 1024;
  const size_t nwp  = (size_t)1024 * 1024;
  const size_t nqkv = (size_t)16384 * 3072;

  bf16* x_bf  = (bf16*)d_ws;
  bf16* wq_bf = x_bf + nx;
  bf16* wp_bf = wq_bf + nwq;
  bf16* qkv   = wp_bf + nwp;
  bf16* attn  = qkv + nqkv;

  (void)hipFuncSetAttribute((const void*)&gemm_bk32<1>,
                            hipFuncAttributeMaxDynamicSharedMemorySize, 65536);
  (void)hipFuncSetAttribute((const void*)&gemm_bk32<0>,
                            hipFuncAttributeMaxDynamicSharedMemorySize, 65536);

  // fused cvt: (nx+nwq+nwp)/4 float4s = 5242880 -> 20480 blocks x 256
  cvt_all<<<20480, 256, 0, stream>>>(x, w_qkv, w_proj, x_bf, wq_bf, wp_bf);

  // qkv = x @ w_qkv^T : M=16384, N=3072, K=1024 ; grid 12x64=768 (%8==0)
  gemm_bk32<1><<<dim3(3072 / 256, 16384 / 256), 512, 65536, stream>>>(
      x_bf, wq_bf, qkv, nullptr, 16384, 3072, 1024);

  // local window attention: 8192 blocks x 256 thr (one (b,h,row) per block)
  local_attn<<<8192, 256, 0, stream>>>(qkv, attn);

  // out = attn @ w_proj^T + b : M=16384, N=1024, K=1024 ; grid 4x64=256 (%8==0)
  gemm_bk32<0><<<dim3(1024 / 256, 16384 / 256), 512, 65536, stream>>>(
      attn, wp_bf, out, b_proj, 16384, 1024, 1024);
}

// Round 13
// 196.471 us; speedup vs baseline: 1.6038x; 1.0640x over previous
//
#include <hip/hip_runtime.h>
#include <hip/hip_bf16.h>
#include <stdint.h>

// LocalAttention: B=16, N=1024 (32x32 grid), C=1024, H=16, D=64.
// cvt->bf16 (fused) ; GEMM1 qkv=x@w_qkv^T (r6 gemm_bk32, 874 TF plateau) ;
// local 3x3 window attention (2-row blocks, 4-lane tokens, all-DPP reduce,
// slot-swizzled LDS) ; GEMM2 out=attn@w_proj^T+b. Workspace ~176 MB.

typedef __bf16 bf16;
typedef __bf16 bf16x4_t __attribute__((ext_vector_type(4)));
typedef __bf16 bf16x8_t __attribute__((ext_vector_type(8)));
typedef float f32x4_t __attribute__((ext_vector_type(4)));

static __device__ __forceinline__ void gload_lds16(const void* g, void* l) {
  __builtin_amdgcn_global_load_lds((__attribute__((address_space(1))) void*)g,
                                   (__attribute__((address_space(3))) void*)l,
                                   16, 0, 0);
}

// raw s_barrier with compile-time memory fences (no vmcnt/lgkm drain)
static __device__ __forceinline__ void block_barrier() {
  asm volatile("" ::: "memory");
  __builtin_amdgcn_s_barrier();
  asm volatile("" ::: "memory");
}

// lane-group add via DPP quad_perm (VALU pipe -- no DS op).
// CTRL 0xB1 = quad_perm[1,0,3,2] (xor 1); 0x4E = quad_perm[2,3,0,1] (xor 2).
template<int CTRL>
static __device__ __forceinline__ float dpp_xor_add(float v) {
  int x = __builtin_amdgcn_update_dpp(0, __float_as_int(v), CTRL, 0xF, 0xF, true);
  return v + __int_as_float(x);
}

// ---------------- fused f32 -> bf16 conversion (x, w_qkv, w_proj) --------------
__global__ void cvt_all(const float* __restrict__ x, const float* __restrict__ wq,
                        const float* __restrict__ wp, bf16* __restrict__ xb,
                        bf16* __restrict__ wqb, bf16* __restrict__ wpb) {
  constexpr int NX = 4194304, NWQ = 786432;          // float4 counts
  int i = blockIdx.x * blockDim.x + threadIdx.x;     // grid exactly covers total
  const float* src; bf16* dst; int off;
  if (i < NX)            { src = x;  dst = xb;  off = i; }
  else if (i < NX + NWQ) { src = wq; dst = wqb; off = i - NX; }
  else                   { src = wp; dst = wpb; off = i - (NX + NWQ); }
  float4 v = reinterpret_cast<const float4*>(src)[off];
  bf16x4_t o;
  o[0] = (bf16)v.x; o[1] = (bf16)v.y; o[2] = (bf16)v.z; o[3] = (bf16)v.w;
  reinterpret_cast<bf16x4_t*>(dst)[off] = o;
}

// ---------------- 256x256 8-wave bf16 GEMM, C = A @ B^T, BK=32 (r6 verbatim) ---
template<int OUT_BF16>
__global__ __launch_bounds__(512, 2)
void gemm_bk32(const bf16* __restrict__ A, const bf16* __restrict__ Bm,
               void* __restrict__ Cout, const float* __restrict__ bias,
               int M, int N, int K) {
  constexpr int SLOT = 32768;                // A 16KB + B 16KB
  extern __shared__ __align__(16) char lds[];

  const int tid = threadIdx.x;
  const int w = tid >> 6, lane = tid & 63;
  const int fr = lane & 15, g = lane >> 4;
  const int wr = w >> 2, wc = w & 3;          // wave grid 2 x 4

  // T1: XCD-aware bijective swizzle (nwg % 8 == 0 for both call sites)
  const int nwg = gridDim.x * gridDim.y;
  int lid = blockIdx.y * gridDim.x + blockIdx.x;
  lid = (lid & 7) * (nwg >> 3) + (lid >> 3);
  const int bx = lid % gridDim.x, by = lid / gridDim.x;
  const int row0 = by * 256, col0 = bx * 256;

  const bf16* Ag = A + (size_t)row0 * K;
  const bf16* Bg = Bm + (size_t)col0 * K;
  const int srow = tid >> 2;                                // 0..127
  const int scol = ((tid & 3) ^ ((tid >> 3) & 3)) * 8;      // inverse-swizzled col
  const int nkt  = K >> 5;                                  // 32

  f32x4_t acc[8][4] = {};

  auto stage = [&](int kt, int slot) {       // 4 gload_lds16 per thread
    const int kb = kt << 5;
    char* sb = lds + slot * SLOT;
    gload_lds16(Ag + (size_t)(srow) * K + kb + scol,       sb + tid * 16);
    gload_lds16(Ag + (size_t)(128 + srow) * K + kb + scol, sb + 8192 + tid * 16);
    gload_lds16(Bg + (size_t)(srow) * K + kb + scol,       sb + 16384 + tid * 16);
    gload_lds16(Bg + (size_t)(128 + srow) * K + kb + scol, sb + 24576 + tid * 16);
  };

  const int uxor = ((fr >> 1) & 3) << 4;   // T2 read-side XOR (lane-constant)

  stage(0, 0);
  stage(1, 1);
  asm volatile("s_waitcnt vmcnt(4)" ::: "memory");
  block_barrier();

  for (int kt = 0; kt < nkt; ++kt) {
    const char* cA = lds + (kt & 1) * SLOT;
    const char* cB = cA + 16384;
    const bool pf = (kt + 2 < nkt);

    bf16x8_t a0[4], a1[4], b0[2], b1[2];
    auto lda = [&](bf16x8_t (&dst)[4], int q) {
#pragma unroll
      for (int i = 0; i < 4; ++i) {
        const int row = wr * 128 + (q * 4 + i) * 16 + fr;
        dst[i] = *reinterpret_cast<const bf16x8_t*>(cA + (row << 6) + ((g << 4) ^ uxor));
      }
    };
    auto ldb = [&](bf16x8_t (&dst)[2], int q) {
#pragma unroll
      for (int j = 0; j < 2; ++j) {
        const int row = wc * 64 + (q * 2 + j) * 16 + fr;
        dst[j] = *reinterpret_cast<const bf16x8_t*>(cB + (row << 6) + ((g << 4) ^ uxor));
      }
    };

    // zig-zag: each fragment read once; b0 held across the tile
    lda(a0, 0);
    ldb(b0, 0);
#pragma unroll
    for (int i = 0; i < 4; ++i)
#pragma unroll
      for (int j = 0; j < 2; ++j)
        acc[i][j] = __builtin_amdgcn_mfma_f32_16x16x32_bf16(a0[i], b0[j], acc[i][j], 0, 0, 0);
    ldb(b1, 1);
#pragma unroll
    for (int i = 0; i < 4; ++i)
#pragma unroll
      for (int j = 0; j < 2; ++j)
        acc[i][2 + j] = __builtin_amdgcn_mfma_f32_16x16x32_bf16(a0[i], b1[j], acc[i][2 + j], 0, 0, 0);
    lda(a1, 1);
#pragma unroll
    for (int i = 0; i < 4; ++i)
#pragma unroll
      for (int j = 0; j < 2; ++j)
        acc[4 + i][2 + j] = __builtin_amdgcn_mfma_f32_16x16x32_bf16(
            a1[i], b1[j], acc[4 + i][2 + j], 0, 0, 0);
#pragma unroll
    for (int i = 0; i < 4; ++i)
#pragma unroll
      for (int j = 0; j < 2; ++j)
        acc[4 + i][j] = __builtin_amdgcn_mfma_f32_16x16x32_bf16(
            a1[i], b0[j], acc[4 + i][j], 0, 0, 0);

    block_barrier();
    if (pf) stage(kt + 2, kt & 1);
    if (kt < nkt - 2) asm volatile("s_waitcnt vmcnt(4)" ::: "memory");
    else              asm volatile("s_waitcnt vmcnt(0)" ::: "memory");
    block_barrier();
  }

  // epilogue: D row = g*4+r (M), col = fr (N) per verified m89 layout
#pragma unroll
  for (int fm = 0; fm < 8; ++fm) {
    const int rbase = row0 + wr * 128 + fm * 16 + g * 4;
#pragma unroll
    for (int fn = 0; fn < 4; ++fn) {
      const int col = col0 + wc * 64 + fn * 16 + fr;
#pragma unroll
      for (int r = 0; r < 4; ++r) {
        const size_t idx = (size_t)(rbase + r) * N + col;
        if constexpr (OUT_BF16) {
          reinterpret_cast<bf16*>(Cout)[idx] = (bf16)acc[fm][fn][r];
        } else {
          reinterpret_cast<float*>(Cout)[idx] = acc[fm][fn][r] + bias[col];
        }
      }
    }
  }
}

// ---------------- local 3x3 window attention (2-row blocks, all-DPP) -----------
// qkv: [B*N][3072] bf16 (q|k|v, head h at h*64). out: [B*N][1024] bf16.
// Block = (b, h, row-pair): 64 tokens, 256 threads = 4 lanes/token x 16 dims.
// Window = 4 grid rows = 128 tokens; K/V staged to LDS (16+16 KB) with 16B-slot
// swizzle: LDS[token][slot] holds global unit (slot ^ (tokcol&7)); reader uses
// slot = unit ^ (tokcol&7) -> the 8 slot positions are evenly covered per wave
// b128 issue (conflict-free phasing possible; linear layout caps at 4 slots).
// Dot reduce = 2 DPP quad_perm adds: ZERO DS shuffle ops in the whole kernel.
__global__ __launch_bounds__(256)
void local_attn(const bf16* __restrict__ qkv, bf16* __restrict__ outp) {
  __shared__ __align__(16) char sK[16384];   // [128 tokens][128 B]
  __shared__ __align__(16) char sV[16384];

  const int tid = threadIdx.x;
  // T1: XCD swizzle (nwg = 4096): same-(b,h) row-pair blocks contiguous per XCD
  int lid = blockIdx.x;
  lid = (lid & 7) * 512 + (lid >> 3);
  const int rp = lid & 15, h = (lid >> 4) & 15, b = lid >> 8;
  const int r0 = rp * 2;

  const bf16* qkvb = qkv + (size_t)(b * 1024) * 3072 + h * 64;

  // ---- stage K/V window rows r0-1 .. r0+2 (clamped), slot-swizzled source ----
  const int tc = tid >> 3;            // token column 0..31
  const int slot = tid & 7;           // LDS 16B-slot within token row
  const int unit = slot ^ (tc & 7);   // global 16B-unit (inverse swizzle)
#pragma unroll
  for (int p = 0; p < 4; ++p) {
    const int jrow = min(max(r0 - 1 + p, 0), 31);
    const bf16* src = qkvb + (size_t)(jrow * 32 + tc) * 3072 + unit * 8;
    gload_lds16(src + 1024, sK + p * 4096 + tid * 16);
    gload_lds16(src + 2048, sV + p * 4096 + tid * 16);
  }

  // ---- q for this thread's token (overlaps staging latency) ----
  const int tok = tid >> 2, ch = tid & 3;        // token 0..63, lane-in-token
  const int row = r0 + (tok >> 5), col = tok & 31;
  const int i = row * 32 + col;
  const bf16* qp = qkvb + (size_t)i * 3072 + ch * 16;
  bf16x8_t q0 = *reinterpret_cast<const bf16x8_t*>(qp);
  bf16x8_t q1 = *reinterpret_cast<const bf16x8_t*>(qp + 8);
  float qf[16];
#pragma unroll
  for (int e = 0; e < 8; ++e) { qf[e] = (float)q0[e]; qf[8 + e] = (float)q1[e]; }

  __syncthreads();   // staging complete (drains vmcnt)

  float s[9];
#pragma unroll
  for (int t = 0; t < 9; ++t) {
    const int dr = t / 3 - 1, dc = t % 3 - 1;
    const int rr = row + dr, cc = col + dc;
    const int ccl = min(max(cc, 0), 31);
    const int wtok = ((tok >> 5) + dr + 1) * 32 + ccl;
    const int key = ccl & 7;
    const char* kb = sK + wtok * 128;
    const bf16x8_t k0 = *reinterpret_cast<const bf16x8_t*>(kb + ((ch * 2) ^ key) * 16);
    const bf16x8_t k1 = *reinterpret_cast<const bf16x8_t*>(kb + ((ch * 2 + 1) ^ key) * 16);
    float ps = 0.f;
#pragma unroll
    for (int e = 0; e < 8; ++e) ps += qf[e] * (float)k0[e];
#pragma unroll
    for (int e = 0; e < 8; ++e) ps += qf[8 + e] * (float)k1[e];
    ps = dpp_xor_add<0xB1>(ps);        // xor 1 (quad_perm, VALU)
    ps = dpp_xor_add<0x4E>(ps);        // xor 2 (quad_perm, VALU) -> full dot
    const bool valid = (rr >= 0 && rr < 32 && cc >= 0 && cc < 32);
    s[t] = ps * 0.125f + (valid ? 0.f : -1e30f);
  }

  float mx = s[0];
#pragma unroll
  for (int t = 1; t < 9; ++t) mx = fmaxf(mx, s[t]);

  float denom = 0.f, o[16] = {};
#pragma unroll
  for (int t = 0; t < 9; ++t) {
    const int dr = t / 3 - 1, dc = t % 3 - 1;
    const int ccl = min(max(col + dc, 0), 31);
    const int wtok = ((tok >> 5) + dr + 1) * 32 + ccl;
    const int key = ccl & 7;
    const float p = __expf(s[t] - mx);       // exp(-huge)=0 for invalid
    denom += p;
    const char* vb = sV + wtok * 128;
    const bf16x8_t v0 = *reinterpret_cast<const bf16x8_t*>(vb + ((ch * 2) ^ key) * 16);
    const bf16x8_t v1 = *reinterpret_cast<const bf16x8_t*>(vb + ((ch * 2 + 1) ^ key) * 16);
#pragma unroll
    for (int e = 0; e < 8; ++e) { o[e] += p * (float)v0[e]; o[8 + e] += p * (float)v1[e]; }
  }

  const float inv = 1.f / denom;
  bf16x8_t ov0, ov1;
#pragma unroll
  for (int e = 0; e < 8; ++e) {
    ov0[e] = (bf16)(o[e] * inv);
    ov1[e] = (bf16)(o[8 + e] * inv);
  }
  bf16* op = outp + (size_t)(b * 1024 + i) * 1024 + h * 64 + ch * 16;
  *reinterpret_cast<bf16x8_t*>(op) = ov0;
  *reinterpret_cast<bf16x8_t*>(op + 8) = ov1;
}

extern "C" void kernel_launch(void* const* d_in, const int* in_sizes, int n_in,
                              void* d_out, int out_size, void* d_ws, size_t ws_size,
                              hipStream_t stream) {
  const float* x      = (const float*)d_in[0];
  const float* w_qkv  = (const float*)d_in[1];
  const float* w_proj = (const float*)d_in[2];
  const float* b_proj = (const float*)d_in[3];
  float* out = (float*)d_out;

  const size_t nx   = (size_t)16384 * 1024;
  const size_t nwq  = (size_t)3072 * 1024;
  const size_t nwp  = (size_t)1024 * 1024;
  const size_t nqkv = (size_t)16384 * 3072;

  bf16* x_bf  = (bf16*)d_ws;
  bf16* wq_bf = x_bf + nx;
  bf16* wp_bf = wq_bf + nwq;
  bf16* qkv   = wp_bf + nwp;
  bf16* attn  = qkv + nqkv;

  (void)hipFuncSetAttribute((const void*)&gemm_bk32<1>,
                            hipFuncAttributeMaxDynamicSharedMemorySize, 65536);
  (void)hipFuncSetAttribute((const void*)&gemm_bk32<0>,
                            hipFuncAttributeMaxDynamicSharedMemorySize, 65536);

  // fused cvt: (nx+nwq+nwp)/4 float4s = 5242880 -> 20480 blocks x 256
  cvt_all<<<20480, 256, 0, stream>>>(x, w_qkv, w_proj, x_bf, wq_bf, wp_bf);

  // qkv = x @ w_qkv^T : M=16384, N=3072, K=1024 ; grid 12x64=768 (%8==0)
  gemm_bk32<1><<<dim3(3072 / 256, 16384 / 256), 512, 65536, stream>>>(
      x_bf, wq_bf, qkv, nullptr, 16384, 3072, 1024);

  // local window attention: 4096 blocks x 256 thr (one (b,h,row-pair)/block)
  local_attn<<<4096, 256, 0, stream>>>(qkv, attn);

  // out = attn @ w_proj^T + b : M=16384, N=1024, K=1024 ; grid 4x64=256 (%8==0)
  gemm_bk32<0><<<dim3(1024 / 256, 16384 / 256), 512, 65536, stream>>>(
      attn, wp_bf, out, b_proj, 16384, 1024, 1024);
}